// Round 1
// baseline (2291.483 us; speedup 1.0000x reference)
//
#include <hip/hip_runtime.h>
#include <math.h>

#define N_NODES 100000
#define N_EDGES 1200000
// F=64 features, HID=64, NCLS=40, K=2 hops

// ---------------------------------------------------------------- degree
__global__ void count_deg(const int* __restrict__ dst, float* __restrict__ deg, int nE) {
    int e = blockIdx.x * blockDim.x + threadIdx.x;
    if (e < nE) atomicAdd(&deg[dst[e]], 1.0f);
}

__global__ void finish_dinv(float* __restrict__ deg, int n) {
    int i = blockIdx.x * blockDim.x + threadIdx.x;
    if (i < n) deg[i] = rsqrtf(deg[i] + 1.0f);  // +1 = self loop; deg>=1 always
}

// ------------------------------------------------- y = dinv[i]^2 * x  (self loop)
__global__ void self_init(float4* __restrict__ y, const float4* __restrict__ x,
                          const float* __restrict__ dinv, int n4) {
    int t = blockIdx.x * blockDim.x + threadIdx.x;  // one float4 (4 feats) per thread
    if (t >= n4) return;
    int node = t >> 4;  // 16 float4 per node (64 feats)
    float w = dinv[node];
    w *= w;
    float4 v = x[t];
    y[t] = make_float4(w * v.x, w * v.y, w * v.z, w * v.w);
}

// ------------------------------------------------- y[dst] += norm * x[src]
__global__ void prop_edges(float* __restrict__ y, const float* __restrict__ x,
                           const int* __restrict__ src, const int* __restrict__ dst,
                           const float* __restrict__ dinv, int nE) {
    int t = blockIdx.x * blockDim.x + threadIdx.x;
    int e = t >> 4;        // 16 threads per edge
    int lane = t & 15;     // each lane: 4 consecutive feats
    if (e >= nE) return;
    int s = src[e], d = dst[e];
    float w = dinv[s] * dinv[d];
    float4 v = reinterpret_cast<const float4*>(x)[(size_t)s * 16 + lane];
    float* yp = y + (size_t)d * 64 + lane * 4;
    atomicAdd(yp + 0, w * v.x);
    atomicAdd(yp + 1, w * v.y);
    atomicAdd(yp + 2, w * v.z);
    atomicAdd(yp + 3, w * v.w);
}

// ------------------------------------------------- MLP + log_softmax, 1 wave/node
__global__ __launch_bounds__(256) void mlp_kernel(
    float* __restrict__ out, const float* __restrict__ xin,
    const float* __restrict__ W1, const float* __restrict__ b1,
    const float* __restrict__ W2, const float* __restrict__ b2, int nN) {
    __shared__ float W1s[64 * 64];
    __shared__ float W2s[64 * 40 + 64];  // +64 pad: lanes 40..63 read garbage safely
    __shared__ float b1s[64];
    __shared__ float b2s[64];
    int tid = threadIdx.x;
    for (int i = tid; i < 64 * 64; i += 256) W1s[i] = W1[i];
    for (int i = tid; i < 64 * 40; i += 256) W2s[i] = W2[i];
    if (tid < 64) b1s[tid] = b1[tid];
    if (tid < 64) b2s[tid] = (tid < 40) ? b2[tid] : 0.0f;
    __syncthreads();

    int w = tid >> 6, lane = tid & 63;
    int gw = blockIdx.x * 4 + w;
    int stride = gridDim.x * 4;
    for (int node = gw; node < nN; node += stride) {
        float xv = xin[(size_t)node * 64 + lane];
        // h = relu(x @ W1 + b1); lane f owns h[f]
        float acc = b1s[lane];
        #pragma unroll
        for (int k = 0; k < 64; ++k)
            acc = fmaf(__shfl(xv, k), W1s[k * 64 + lane], acc);
        float h = fmaxf(acc, 0.0f);
        // logits = h @ W2 + b2; lane c (<40) owns logit[c]
        float acc2 = b2s[lane];
        #pragma unroll
        for (int k = 0; k < 64; ++k)
            acc2 = fmaf(__shfl(h, k), W2s[k * 40 + lane], acc2);
        float logit = (lane < 40) ? acc2 : -INFINITY;
        // log_softmax over 40 classes (pad lanes: -inf -> exp 0)
        float m = logit;
        #pragma unroll
        for (int off = 1; off < 64; off <<= 1)
            m = fmaxf(m, __shfl_xor(m, off));
        float p = expf(logit - m);
        float ssum = p;
        #pragma unroll
        for (int off = 1; off < 64; off <<= 1)
            ssum += __shfl_xor(ssum, off);
        if (lane < 40)
            out[(size_t)node * 40 + lane] = logit - m - logf(ssum);
    }
}

extern "C" void kernel_launch(void* const* d_in, const int* in_sizes, int n_in,
                              void* d_out, int out_size, void* d_ws, size_t ws_size,
                              hipStream_t stream) {
    const float* x   = (const float*)d_in[0];
    const int* eidx  = (const int*)d_in[1];
    const float* W1  = (const float*)d_in[2];
    const float* b1  = (const float*)d_in[3];
    const float* W2  = (const float*)d_in[4];
    const float* b2  = (const float*)d_in[5];
    float* out = (float*)d_out;

    const int nN = N_NODES;
    const int nE = in_sizes[1] / 2;  // edge_index is [2, E]
    const int* src = eidx;
    const int* dst = eidx + nE;

    // workspace layout (256B aligned)
    char* ws = (char*)d_ws;
    float* dinv = (float*)ws;                                   // nN floats
    size_t off = ((size_t)nN * 4 + 255) & ~(size_t)255;
    float* bufA = (float*)(ws + off);                           // nN*64 floats
    float* bufB = bufA + (size_t)nN * 64;                       // nN*64 floats

    // 1. degree -> dinv
    hipMemsetAsync(dinv, 0, (size_t)nN * 4, stream);
    count_deg<<<(nE + 255) / 256, 256, 0, stream>>>(dst, dinv, nE);
    finish_dinv<<<(nN + 255) / 256, 256, 0, stream>>>(dinv, nN);

    const int n4 = nN * 16;                 // float4 elements per feature buffer
    const int initBlocks = (n4 + 255) / 256;
    const int propBlocks = (nE * 16 + 255) / 256;

    // 2. hop 1: bufA = dinv^2*x + scatter(norm * x[src])
    self_init<<<initBlocks, 256, 0, stream>>>((float4*)bufA, (const float4*)x, dinv, n4);
    prop_edges<<<propBlocks, 256, 0, stream>>>(bufA, x, src, dst, dinv, nE);

    // 3. hop 2: bufB from bufA
    self_init<<<initBlocks, 256, 0, stream>>>((float4*)bufB, (const float4*)bufA, dinv, n4);
    prop_edges<<<propBlocks, 256, 0, stream>>>(bufB, bufA, src, dst, dinv, nE);

    // 4. MLP + log_softmax
    mlp_kernel<<<2048, 256, 0, stream>>>(out, bufB, W1, b1, W2, b2, nN);
}

// Round 2
// 455.943 us; speedup vs baseline: 5.0258x; 5.0258x over previous
//
#include <hip/hip_runtime.h>
#include <math.h>

#define N_NODES 100000

// ---------------------------------------------------------------- degree histogram (int)
__global__ void count_deg(const int* __restrict__ dst, int* __restrict__ deg, int nE) {
    int e = blockIdx.x * blockDim.x + threadIdx.x;
    if (e < nE) atomicAdd(&deg[dst[e]], 1);
}

__global__ void finish_dinv(const int* __restrict__ deg, float* __restrict__ dinv, int n) {
    int i = blockIdx.x * blockDim.x + threadIdx.x;
    if (i < n) dinv[i] = rsqrtf((float)deg[i] + 1.0f);  // +1 = self loop
}

// ---------------------------------------------------------------- exclusive scan (3 kernels)
__global__ void scan_local(const int* __restrict__ deg, int* __restrict__ rowptr,
                           int* __restrict__ partials, int n /* = nN */) {
    __shared__ int s[256];
    int i = blockIdx.x * 256 + threadIdx.x;       // scanning n+1 virtual elements
    int v = (i < n) ? deg[i] : 0;
    s[threadIdx.x] = v;
    __syncthreads();
    #pragma unroll
    for (int off = 1; off < 256; off <<= 1) {
        int t = (threadIdx.x >= off) ? s[threadIdx.x - off] : 0;
        __syncthreads();
        s[threadIdx.x] += t;
        __syncthreads();
    }
    if (i <= n) rowptr[i] = s[threadIdx.x] - v;   // exclusive
    if (threadIdx.x == 255) partials[blockIdx.x] = s[255];
}

__global__ void scan_partials(int* __restrict__ partials, int nB) {
    __shared__ int s[512];
    int v = (threadIdx.x < nB) ? partials[threadIdx.x] : 0;
    s[threadIdx.x] = v;
    __syncthreads();
    #pragma unroll
    for (int off = 1; off < 512; off <<= 1) {
        int t = (threadIdx.x >= off) ? s[threadIdx.x - off] : 0;
        __syncthreads();
        s[threadIdx.x] += t;
        __syncthreads();
    }
    if (threadIdx.x < nB) partials[threadIdx.x] = s[threadIdx.x] - v;  // exclusive
}

__global__ void add_offsets(int* __restrict__ rowptr, const int* __restrict__ partials, int m) {
    int i = blockIdx.x * 256 + threadIdx.x;
    if (i < m) rowptr[i] += partials[blockIdx.x];
}

// ---------------------------------------------------------------- scatter edges into CSR
__global__ void scatter_edges(const int* __restrict__ src, const int* __restrict__ dst,
                              const int* __restrict__ rowptr, int* __restrict__ cursor,
                              int* __restrict__ nbr, int nE) {
    int e = blockIdx.x * blockDim.x + threadIdx.x;
    if (e >= nE) return;
    int d = dst[e];
    int pos = rowptr[d] + atomicAdd(&cursor[d], 1);
    nbr[pos] = src[e];
}

// ---------------------------------------------------------------- z0 = dinv * x
__global__ void scale_x(float4* __restrict__ z, const float4* __restrict__ x,
                        const float* __restrict__ dinv, int n4) {
    int t = blockIdx.x * blockDim.x + threadIdx.x;
    if (t >= n4) return;
    float w = dinv[t >> 4];
    float4 v = x[t];
    z[t] = make_float4(w * v.x, w * v.y, w * v.z, w * v.w);
}

// ---------------------------------------------------------------- gather hop: out = w * (z[self] + sum z[nbr])
__global__ __launch_bounds__(256) void gather_hop(
    float* __restrict__ out, const float* __restrict__ z,
    const int* __restrict__ nbr, const int* __restrict__ rowptr,
    const float* __restrict__ dinv, int nN, int pw) {
    int node = blockIdx.x * 4 + (threadIdx.x >> 6);
    if (node >= nN) return;
    int lane = threadIdx.x & 63;
    int beg = rowptr[node], end = rowptr[node + 1];
    float acc0 = z[(size_t)node * 64 + lane];   // self loop
    float acc1 = 0.0f;
    int j = beg;
    for (; j + 2 <= end; j += 2) {              // 2-way unroll for load ILP
        int s0 = nbr[j], s1 = nbr[j + 1];
        acc0 += z[(size_t)s0 * 64 + lane];
        acc1 += z[(size_t)s1 * 64 + lane];
    }
    if (j < end) acc0 += z[(size_t)nbr[j] * 64 + lane];
    float w = dinv[node];
    if (pw == 2) w *= w;
    out[(size_t)node * 64 + lane] = (acc0 + acc1) * w;
}

// ---------------------------------------------------------------- MLP + log_softmax, 1 wave/node
__global__ __launch_bounds__(256) void mlp_kernel(
    float* __restrict__ out, const float* __restrict__ xin,
    const float* __restrict__ W1, const float* __restrict__ b1,
    const float* __restrict__ W2, const float* __restrict__ b2, int nN) {
    __shared__ float W1s[64 * 64];
    __shared__ float W2s[64 * 40 + 64];
    __shared__ float b1s[64];
    __shared__ float b2s[64];
    int tid = threadIdx.x;
    for (int i = tid; i < 64 * 64; i += 256) W1s[i] = W1[i];
    for (int i = tid; i < 64 * 40; i += 256) W2s[i] = W2[i];
    if (tid < 64) b1s[tid] = b1[tid];
    if (tid < 64) b2s[tid] = (tid < 40) ? b2[tid] : 0.0f;
    __syncthreads();

    int w = tid >> 6, lane = tid & 63;
    int gw = blockIdx.x * 4 + w;
    int stride = gridDim.x * 4;
    for (int node = gw; node < nN; node += stride) {
        float xv = xin[(size_t)node * 64 + lane];
        float acc = b1s[lane];
        #pragma unroll
        for (int k = 0; k < 64; ++k)
            acc = fmaf(__shfl(xv, k), W1s[k * 64 + lane], acc);
        float h = fmaxf(acc, 0.0f);
        float acc2 = b2s[lane];
        #pragma unroll
        for (int k = 0; k < 64; ++k)
            acc2 = fmaf(__shfl(h, k), W2s[k * 40 + lane], acc2);
        float logit = (lane < 40) ? acc2 : -INFINITY;
        float m = logit;
        #pragma unroll
        for (int off = 1; off < 64; off <<= 1)
            m = fmaxf(m, __shfl_xor(m, off));
        float p = expf(logit - m);
        float ssum = p;
        #pragma unroll
        for (int off = 1; off < 64; off <<= 1)
            ssum += __shfl_xor(ssum, off);
        if (lane < 40)
            out[(size_t)node * 40 + lane] = logit - m - logf(ssum);
    }
}

extern "C" void kernel_launch(void* const* d_in, const int* in_sizes, int n_in,
                              void* d_out, int out_size, void* d_ws, size_t ws_size,
                              hipStream_t stream) {
    const float* x   = (const float*)d_in[0];
    const int* eidx  = (const int*)d_in[1];
    const float* W1  = (const float*)d_in[2];
    const float* b1  = (const float*)d_in[3];
    const float* W2  = (const float*)d_in[4];
    const float* b2  = (const float*)d_in[5];
    float* out = (float*)d_out;

    const int nN = N_NODES;
    const int nE = in_sizes[1] / 2;  // edge_index is [2, E]
    const int* src = eidx;
    const int* dst = eidx + nE;

    // ---- workspace layout (all 256B aligned)
    char* ws = (char*)d_ws;
    size_t off = 0;
    auto alloc = [&](size_t bytes) {
        char* p = ws + off;
        off += (bytes + 255) & ~(size_t)255;
        return p;
    };
    float* dinv    = (float*)alloc((size_t)nN * 4);
    int*   deg     = (int*)  alloc((size_t)nN * 4);      // later reused as scatter cursor
    int*   rowptr  = (int*)  alloc((size_t)(nN + 1) * 4);
    int*   partials= (int*)  alloc(512 * 4);
    int*   nbr     = (int*)  alloc((size_t)nE * 4);
    float* zA      = (float*)alloc((size_t)nN * 64 * 4);
    float* zB      = (float*)alloc((size_t)nN * 64 * 4);

    const int nB = (nN + 1 + 255) / 256;   // scan blocks over nN+1 elements

    // 1. degree histogram + dinv
    hipMemsetAsync(deg, 0, (size_t)nN * 4, stream);
    count_deg<<<(nE + 255) / 256, 256, 0, stream>>>(dst, deg, nE);
    finish_dinv<<<(nN + 255) / 256, 256, 0, stream>>>(deg, dinv, nN);

    // 2. rowptr = exclusive scan(deg), nN+1 entries
    scan_local<<<nB, 256, 0, stream>>>(deg, rowptr, partials, nN);
    scan_partials<<<1, 512, 0, stream>>>(partials, nB);
    add_offsets<<<nB, 256, 0, stream>>>(rowptr, partials, nN + 1);

    // 3. scatter edges into CSR adjacency (deg reused as cursor)
    hipMemsetAsync(deg, 0, (size_t)nN * 4, stream);
    scatter_edges<<<(nE + 255) / 256, 256, 0, stream>>>(src, dst, rowptr, deg, nbr, nE);

    // 4. z0 = dinv * x
    const int n4 = nN * 16;
    scale_x<<<(n4 + 255) / 256, 256, 0, stream>>>((float4*)zA, (const float4*)x, dinv, n4);

    // 5. two gather hops: zB = dinv^2*(Â zA); zA = dinv*(Â zB)
    const int gBlocks = (nN + 3) / 4;
    gather_hop<<<gBlocks, 256, 0, stream>>>(zB, zA, nbr, rowptr, dinv, nN, 2);
    gather_hop<<<gBlocks, 256, 0, stream>>>(zA, zB, nbr, rowptr, dinv, nN, 1);

    // 6. MLP + log_softmax
    mlp_kernel<<<2048, 256, 0, stream>>>(out, zA, W1, b1, W2, b2, nN);
}

// Round 3
// 287.342 us; speedup vs baseline: 7.9748x; 1.5868x over previous
//
#include <hip/hip_runtime.h>
#include <math.h>

#define N_NODES 100000

// ---------------------------------------------------------------- degree histogram (int)
__global__ void count_deg(const int* __restrict__ dst, int* __restrict__ deg, int nE) {
    int e = blockIdx.x * blockDim.x + threadIdx.x;
    if (e < nE) atomicAdd(&deg[dst[e]], 1);
}

__global__ void finish_dinv(const int* __restrict__ deg, float* __restrict__ dinv, int n) {
    int i = blockIdx.x * blockDim.x + threadIdx.x;
    if (i < n) dinv[i] = rsqrtf((float)deg[i] + 1.0f);  // +1 = self loop
}

// ---------------------------------------------------------------- exclusive scan (3 kernels)
__global__ void scan_local(const int* __restrict__ deg, int* __restrict__ rowptr,
                           int* __restrict__ partials, int n) {
    __shared__ int s[256];
    int i = blockIdx.x * 256 + threadIdx.x;
    int v = (i < n) ? deg[i] : 0;
    s[threadIdx.x] = v;
    __syncthreads();
    #pragma unroll
    for (int off = 1; off < 256; off <<= 1) {
        int t = (threadIdx.x >= off) ? s[threadIdx.x - off] : 0;
        __syncthreads();
        s[threadIdx.x] += t;
        __syncthreads();
    }
    if (i <= n) rowptr[i] = s[threadIdx.x] - v;   // exclusive
    if (threadIdx.x == 255) partials[blockIdx.x] = s[255];
}

__global__ void scan_partials(int* __restrict__ partials, int nB) {
    __shared__ int s[512];
    int v = (threadIdx.x < nB) ? partials[threadIdx.x] : 0;
    s[threadIdx.x] = v;
    __syncthreads();
    #pragma unroll
    for (int off = 1; off < 512; off <<= 1) {
        int t = (threadIdx.x >= off) ? s[threadIdx.x - off] : 0;
        __syncthreads();
        s[threadIdx.x] += t;
        __syncthreads();
    }
    if (threadIdx.x < nB) partials[threadIdx.x] = s[threadIdx.x] - v;
}

__global__ void add_offsets(int* __restrict__ rowptr, const int* __restrict__ partials, int m) {
    int i = blockIdx.x * 256 + threadIdx.x;
    if (i < m) rowptr[i] += partials[blockIdx.x];
}

// ---------------------------------------------------------------- scatter edges into CSR
__global__ void scatter_edges(const int* __restrict__ src, const int* __restrict__ dst,
                              const int* __restrict__ rowptr, int* __restrict__ cursor,
                              int* __restrict__ nbr, int nE) {
    int e = blockIdx.x * blockDim.x + threadIdx.x;
    if (e >= nE) return;
    int d = dst[e];
    int pos = rowptr[d] + atomicAdd(&cursor[d], 1);
    nbr[pos] = src[e];
}

// ---------------------------------------------------------------- gather hop
// WSRC: weight each gathered row by dinv[src] (and self by dinv[node])
// PW:   final diagonal scale dinv^PW
template<bool WSRC, int PW>
__global__ __launch_bounds__(256) void gather_hop(
    float* __restrict__ out, const float* __restrict__ z,
    const int* __restrict__ nbr, const int* __restrict__ rowptr,
    const float* __restrict__ dinv, int nN) {
    int node = blockIdx.x * 4 + (threadIdx.x >> 6);
    if (node >= nN) return;
    int lane = threadIdx.x & 63;
    int beg = rowptr[node], end = rowptr[node + 1];
    float di = dinv[node];
    float self = z[(size_t)node * 64 + lane];
    float a0 = WSRC ? di * self : self;
    float a1 = 0.f, a2 = 0.f, a3 = 0.f;
    int j = beg;
    for (; j + 4 <= end; j += 4) {          // 4 outstanding row loads
        int s0 = nbr[j], s1 = nbr[j + 1], s2 = nbr[j + 2], s3 = nbr[j + 3];
        float v0 = z[(size_t)s0 * 64 + lane];
        float v1 = z[(size_t)s1 * 64 + lane];
        float v2 = z[(size_t)s2 * 64 + lane];
        float v3 = z[(size_t)s3 * 64 + lane];
        if (WSRC) {
            a0 = fmaf(dinv[s0], v0, a0);
            a1 = fmaf(dinv[s1], v1, a1);
            a2 = fmaf(dinv[s2], v2, a2);
            a3 = fmaf(dinv[s3], v3, a3);
        } else {
            a0 += v0; a1 += v1; a2 += v2; a3 += v3;
        }
    }
    for (; j < end; ++j) {
        int s = nbr[j];
        float v = z[(size_t)s * 64 + lane];
        a0 = WSRC ? fmaf(dinv[s], v, a0) : a0 + v;
    }
    float w = (PW == 2) ? di * di : di;
    out[(size_t)node * 64 + lane] = (a0 + a1 + a2 + a3) * w;
}

// ---------------------------------------------------------------- fused MLP + log_softmax
// block = 256 threads = 64 nodes; register-tiled 4x4 GEMM, h round-trips via LDS
__global__ __launch_bounds__(256) void mlp_fused(
    float* __restrict__ out, const float* __restrict__ xin,
    const float* __restrict__ W1, const float* __restrict__ b1,
    const float* __restrict__ W2, const float* __restrict__ b2, int nN) {
    __shared__ float xT[64][68];    // xT[k][n]; stride 68 keeps float4 alignment
    __shared__ float W1s[64][64];
    __shared__ float W2s[64][40];
    __shared__ float b1s[64];
    __shared__ float b2s[40];
    int tid = threadIdx.x;
    int base = blockIdx.x * 64;

    for (int i = tid; i < 64 * 64; i += 256) W1s[i >> 6][i & 63] = W1[i];
    for (int i = tid; i < 64 * 40; i += 256) W2s[i / 40][i % 40] = W2[i];
    if (tid < 64) b1s[tid] = b1[tid];
    if (tid >= 64 && tid < 104) b2s[tid - 64] = b2[tid - 64];

    {   // load x tile transposed: thread -> node tid>>2, k-chunk (tid&3)*16
        int n = tid >> 2;
        int kq = (tid & 3) * 4;             // float4 index base within row
        int gn = base + n;
        #pragma unroll
        for (int r = 0; r < 4; ++r) {
            float4 v = make_float4(0.f, 0.f, 0.f, 0.f);
            if (gn < nN) v = reinterpret_cast<const float4*>(xin)[(size_t)gn * 16 + kq + r];
            int kk = (kq + r) * 4;
            xT[kk + 0][n] = v.x; xT[kk + 1][n] = v.y;
            xT[kk + 2][n] = v.z; xT[kk + 3][n] = v.w;
        }
    }
    __syncthreads();

    // stage 1: h = relu(x @ W1 + b1); thread owns 4 nodes x 4 hids
    int h0 = (tid & 15) * 4, n0 = (tid >> 4) * 4;
    float acc[4][4];
    #pragma unroll
    for (int i = 0; i < 4; ++i)
        #pragma unroll
        for (int j = 0; j < 4; ++j) acc[i][j] = b1s[h0 + j];
    #pragma unroll 8
    for (int k = 0; k < 64; ++k) {
        float4 xv = *reinterpret_cast<const float4*>(&xT[k][n0]);
        float4 wv = *reinterpret_cast<const float4*>(&W1s[k][h0]);
        acc[0][0] = fmaf(xv.x, wv.x, acc[0][0]);
        acc[0][1] = fmaf(xv.x, wv.y, acc[0][1]);
        acc[0][2] = fmaf(xv.x, wv.z, acc[0][2]);
        acc[0][3] = fmaf(xv.x, wv.w, acc[0][3]);
        acc[1][0] = fmaf(xv.y, wv.x, acc[1][0]);
        acc[1][1] = fmaf(xv.y, wv.y, acc[1][1]);
        acc[1][2] = fmaf(xv.y, wv.z, acc[1][2]);
        acc[1][3] = fmaf(xv.y, wv.w, acc[1][3]);
        acc[2][0] = fmaf(xv.z, wv.x, acc[2][0]);
        acc[2][1] = fmaf(xv.z, wv.y, acc[2][1]);
        acc[2][2] = fmaf(xv.z, wv.z, acc[2][2]);
        acc[2][3] = fmaf(xv.z, wv.w, acc[2][3]);
        acc[3][0] = fmaf(xv.w, wv.x, acc[3][0]);
        acc[3][1] = fmaf(xv.w, wv.y, acc[3][1]);
        acc[3][2] = fmaf(xv.w, wv.z, acc[3][2]);
        acc[3][3] = fmaf(xv.w, wv.w, acc[3][3]);
    }
    __syncthreads();                    // everyone done READING xT
    #pragma unroll
    for (int i = 0; i < 4; ++i)
        #pragma unroll
        for (int j = 0; j < 4; ++j)
            xT[h0 + j][n0 + i] = fmaxf(acc[i][j], 0.f);   // hT[hid][node], reuse xT
    __syncthreads();

    // stage 2: logits + log_softmax; 4 threads per node, 10 classes each
    int n2 = tid >> 2, q = tid & 3;
    float lg[10];
    #pragma unroll
    for (int c = 0; c < 10; ++c) lg[c] = b2s[q * 10 + c];
    #pragma unroll 4
    for (int k = 0; k < 64; ++k) {
        float hv = xT[k][n2];
        #pragma unroll
        for (int c = 0; c < 10; ++c)
            lg[c] = fmaf(hv, W2s[k][q * 10 + c], lg[c]);
    }
    float m = lg[0];
    #pragma unroll
    for (int c = 1; c < 10; ++c) m = fmaxf(m, lg[c]);
    m = fmaxf(m, __shfl_xor(m, 1));
    m = fmaxf(m, __shfl_xor(m, 2));
    float s = 0.f;
    #pragma unroll
    for (int c = 0; c < 10; ++c) s += expf(lg[c] - m);
    s += __shfl_xor(s, 1);
    s += __shfl_xor(s, 2);
    float lse = m + logf(s);
    int gn = base + n2;
    if (gn < nN) {
        #pragma unroll
        for (int c = 0; c < 10; ++c)
            out[(size_t)gn * 40 + q * 10 + c] = lg[c] - lse;
    }
}

extern "C" void kernel_launch(void* const* d_in, const int* in_sizes, int n_in,
                              void* d_out, int out_size, void* d_ws, size_t ws_size,
                              hipStream_t stream) {
    const float* x   = (const float*)d_in[0];
    const int* eidx  = (const int*)d_in[1];
    const float* W1  = (const float*)d_in[2];
    const float* b1  = (const float*)d_in[3];
    const float* W2  = (const float*)d_in[4];
    const float* b2  = (const float*)d_in[5];
    float* out = (float*)d_out;

    const int nN = N_NODES;
    const int nE = in_sizes[1] / 2;  // edge_index is [2, E]
    const int* src = eidx;
    const int* dst = eidx + nE;

    // ---- workspace layout (256B aligned)
    char* ws = (char*)d_ws;
    size_t off = 0;
    auto alloc = [&](size_t bytes) {
        char* p = ws + off;
        off += (bytes + 255) & ~(size_t)255;
        return p;
    };
    float* dinv    = (float*)alloc((size_t)nN * 4);
    int*   deg     = (int*)  alloc((size_t)nN * 4);      // reused as scatter cursor
    int*   rowptr  = (int*)  alloc((size_t)(nN + 1) * 4);
    int*   partials= (int*)  alloc(512 * 4);
    int*   nbr     = (int*)  alloc((size_t)nE * 4);
    float* zB      = (float*)alloc((size_t)nN * 64 * 4);
    float* zC      = (float*)alloc((size_t)nN * 64 * 4);

    const int nB = (nN + 1 + 255) / 256;

    // 1. degree histogram + dinv
    hipMemsetAsync(deg, 0, (size_t)nN * 4, stream);
    count_deg<<<(nE + 255) / 256, 256, 0, stream>>>(dst, deg, nE);
    finish_dinv<<<(nN + 255) / 256, 256, 0, stream>>>(deg, dinv, nN);

    // 2. rowptr = exclusive scan(deg)
    scan_local<<<nB, 256, 0, stream>>>(deg, rowptr, partials, nN);
    scan_partials<<<1, 512, 0, stream>>>(partials, nB);
    add_offsets<<<nB, 256, 0, stream>>>(rowptr, partials, nN + 1);

    // 3. scatter edges into CSR (deg reused as cursor)
    hipMemsetAsync(deg, 0, (size_t)nN * 4, stream);
    scatter_edges<<<(nE + 255) / 256, 256, 0, stream>>>(src, dst, rowptr, deg, nbr, nE);

    // 4. hop1: zB = D^-1 (A+I) D^-1/2 x   (dinv[src] folded into gather)
    //    hop2: zC = D^-1/2 (A+I) zB
    const int gBlocks = (nN + 3) / 4;
    gather_hop<true, 2><<<gBlocks, 256, 0, stream>>>(zB, x, nbr, rowptr, dinv, nN);
    gather_hop<false, 1><<<gBlocks, 256, 0, stream>>>(zC, zB, nbr, rowptr, dinv, nN);

    // 5. fused MLP + log_softmax
    mlp_fused<<<(nN + 63) / 64, 256, 0, stream>>>(out, zC, W1, b1, W2, b2, nN);
}